// Round 5
// baseline (535.335 us; speedup 1.0000x reference)
//
#include <hip/hip_runtime.h>

#define E 300
#define P 5
#define H 200
#define S 256
#define L 34
#define B 8
#define NI 254    // pivot positions i = 1..254
#define NBLK 1024 // 4 blocks/CU x 256 CU co-resident (64 VGPR, 25.6KB LDS)
#define NGRP 16   // barrier groups of 64 blocks

typedef __attribute__((ext_vector_type(8))) _Float16 half8;
typedef __attribute__((ext_vector_type(2))) _Float16 h2;
typedef __attribute__((ext_vector_type(4))) float f32x4;

// ws layout (float units; all f16 arrays)
#define TOKB_OFF   0            // tokb f16[8][258][300] (+slack)
#define WR3_OFF    309632       // Wr3[208][928] f16
#define FCWB_OFF   406144       // fcWb[48][1344] f16
#define G_OFF      438400       // g f16[512][200]
#define C0_OFF     489600       // c0 f16[254][200]
#define C255_OFF   515000       // c255 f16[254][200]
#define CT_OFF     540400       // ct f16[b][j][h]
#define POOLF_OFF  745200       // poolf f16[b][256][416]
#define BAR_OFF    2000000      // barrier counters: 3 phases x 4KB

__device__ __forceinline__ unsigned short f2h(float f) {
    _Float16 h = (_Float16)f;               // RNE
    unsigned short u; __builtin_memcpy(&u, &h, 2);
    return u;
}
__device__ __forceinline__ h2 u2h2(unsigned u) {
    h2 h; __builtin_memcpy(&h, &u, 4); return h;
}
__device__ __forceinline__ unsigned h2u(h2 h) {
    unsigned u; __builtin_memcpy(&u, &h, 4); return u;
}
__device__ __forceinline__ h2 hmax2(h2 a, h2 b) {
    return __builtin_elementwise_max(a, b);  // v_pk_max_f16
}
__device__ __forceinline__ half8 load_h8(const unsigned short* p) {
    half8 r;
    ((ushort4*)&r)[0] = *(const ushort4*)p;  // rows are 8B-aligned
    ((ushort4*)&r)[1] = *(const ushort4*)(p + 4);
    return r;
}

// stage-A virtual 256-thread blocks
#define GA_BLOCKS   605   // gather: 154800 items
#define WR3_BLOCKS  754   // Wr3 repack: 193024 items
#define FCW_BLOCKS  252   // fcWb repack: 64512 items
#define PREP_BLOCKS 64    // factored g/c0/c255: 1020 rows x 200 h
#define INIT_VB (GA_BLOCKS + WR3_BLOCKS + FCW_BLOCKS + PREP_BLOCKS)  // 1675

// Two-level software grid barrier (validated single-level in R3; hierarchical
// to keep 1024-way contention off one cacheline). Agent-scope ACQ_REL chain:
// block release->group ctr, group leader release->global, spinners acquire.
// Bounded spin = deadlock fuse (fails visibly, never hangs).
__device__ __forceinline__ void gbar(unsigned* bar, int phase) {
    __syncthreads();
    if (threadIdx.x == 0) {
        unsigned* base = bar + phase * 1024;
        unsigned* c1 = base + (blockIdx.x >> 6) * 16;   // 64B apart
        unsigned* c2 = base + 1008;
        unsigned prev = __hip_atomic_fetch_add(c1, 1u, __ATOMIC_ACQ_REL,
                                               __HIP_MEMORY_SCOPE_AGENT);
        if (prev == 63)
            __hip_atomic_fetch_add(c2, 1u, __ATOMIC_ACQ_REL,
                                   __HIP_MEMORY_SCOPE_AGENT);
        unsigned t = 0;
        while (__hip_atomic_load(c2, __ATOMIC_ACQUIRE,
                                 __HIP_MEMORY_SCOPE_AGENT) < NGRP) {
            __builtin_amdgcn_s_sleep(4);
            if (++t > (1u << 22)) break;   // fuse
        }
    }
    __syncthreads();
}

// Fused pipeline: init -> conv GEMM -> dynamic pool -> fc GEMM. 1024 blocks x
// 512 thr; launch_bounds(512,8) caps VGPR at 64 (R3 binary already fit) =>
// 4 blocks/CU co-resident. Each stage runs at its standalone occupancy.
__global__ __launch_bounds__(512, 8) void k_fused(
        const int* __restrict__ ids,
        const float* __restrict__ we,
        const float* __restrict__ convW,
        const float* __restrict__ fcW,
        const float* __restrict__ pf,
        const float* __restrict__ convB,
        const float* __restrict__ fcB,
        unsigned short* __restrict__ tokb,
        unsigned short* __restrict__ Wr3,
        unsigned short* __restrict__ fcWb,
        unsigned short* __restrict__ g,
        unsigned short* __restrict__ c0,
        unsigned short* __restrict__ c255,
        unsigned short* __restrict__ ct,
        unsigned short* __restrict__ poolf,
        float* __restrict__ out,
        unsigned* bar) {
    __shared__ __align__(16) unsigned char smem[25600];
    float4* cld = (float4*)smem;               // stages B & D
    uint2*  lds2 = (uint2*)smem;               // stage C

    const int bid = blockIdx.x;
    const int tid = threadIdx.x;

    // ================= Stage A: init (2048 virtual 256-thr blocks) ============
    {
        int half = tid >> 8;                   // two vblocks per physical block
        int t    = tid & 255;
        int vb   = bid * 2 + half;
        if (vb < GA_BLOCKS) {
            // tokb f16[b][258][300], rows 0 & 257 zero
            int idx = vb * 256 + t;
            if (idx < B * 258 * 75) {
                int row = idx / 75;
                int col = idx - row * 75;
                int b = row / 258;
                int r = row - b * 258;
                float4 v = make_float4(0.f, 0.f, 0.f, 0.f);
                if (r >= 1 && r <= 256) {
                    int id = ids[b * S + (r - 1)];
                    v = ((const float4*)we)[(size_t)id * 75 + col];
                }
                ushort4 o;
                o.x = f2h(v.x); o.y = f2h(v.y); o.z = f2h(v.z); o.w = f2h(v.w);
                *(ushort4*)(tokb + (size_t)row * 300 + col * 4) = o;
            }
        } else if (vb < GA_BLOCKS + WR3_BLOCKS) {      // Wr3: 208x928
            int idx = (vb - GA_BLOCKS) * 256 + t;
            if (idx < 193024) {
                int hh = idx / 928, kk = idx - hh * 928;
                float v = 0.f;
                if (hh < H && kk < 900) {
                    int r = kk / 300, e = kk - r * 300;
                    v = convW[hh * 915 + e * 3 + r];
                }
                Wr3[idx] = f2h(v);
            }
        } else if (vb < GA_BLOCKS + WR3_BLOCKS + FCW_BLOCKS) {  // fcWb: 48x1344
            int t2 = (vb - GA_BLOCKS - WR3_BLOCKS) * 256 + t;
            if (t2 < 64512) {
                int l = t2 / 1344, c = t2 - l * 1344;
                float v = 0.f;
                if (l < L) {
                    if (c < 400) v = fcW[l * 1300 + c];
                    else if (c >= 416 && c < 1316) v = fcW[l * 1300 + 400 + (c - 416)];
                }
                fcWb[t2] = f2h(v);
            }
        } else if (vb < INIT_VB) {
            // factored prep: per-h convW slice (15 f32) in REGISTERS, shared
            // across 16 rows; pf reads are wave-uniform broadcasts.
            if (t < 200) {
                int h = t;
                float cw[15];
                const float* src = convW + h * 915 + 900;
#pragma unroll
                for (int i = 0; i < 15; i++) cw[i] = src[i];
                int pb = vb - (GA_BLOCKS + WR3_BLOCKS + FCW_BLOCKS);
#pragma unroll 1
                for (int rl = 0; rl < 16; rl++) {
                    int rg = pb * 16 + rl;
                    if (rg >= 1020) break;
                    float a = 0.f;
                    if (rg < 512) {                          // g row t2 = rg
                        int d = rg - 256;
#pragma unroll
                        for (int k = 0; k < 3; k++) {
                            int r = d + k - 1; r = (r < 0) ? -r : r; if (r > 255) r = 255;
#pragma unroll
                            for (int q = 0; q < P; q++)
                                a += cw[q * 3 + k] * pf[r * P + q];
                        }
                        g[rg * H + h] = f2h(a);
                    } else if (rg < 766) {                   // c0 row m, i=m+1
                        int m = rg - 512, i = m + 1;
#pragma unroll
                        for (int q = 0; q < P; q++) {
                            a += cw[q * 3 + 1] * pf[i * P + q];
                            a += cw[q * 3 + 2] * pf[(i - 1) * P + q];
                        }
                        c0[m * H + h] = f2h(a);
                    } else {                                 // c255 row m, i=m+1
                        int m = rg - 766, i = m + 1;
#pragma unroll
                        for (int q = 0; q < P; q++) {
                            a += cw[q * 3 + 0] * pf[(254 - i) * P + q];
                            a += cw[q * 3 + 1] * pf[(255 - i) * P + q];
                        }
                        c255[m * H + h] = f2h(a);
                    }
                }
            }
        }
    }
    gbar(bar, 0);

    // ================= Stage B: conv GEMM (416 virtual blocks) ================
    if (bid < 416) {
        int n0 = (bid % 13) * 16;
        int mg = bid / 13;
        int wave = tid >> 6;
        int lane = tid & 63;
        int mt = wave & 3;
        int kh = wave >> 2;
        int quad = lane >> 4;
        int lr = lane & 15;
        int mtile = mg * 4 + mt;
        int b = mtile >> 4;
        int j0 = (mtile & 15) << 4;

        const unsigned short* pa = tokb + ((size_t)(b * 258 + j0 + lr) * 300 + quad * 8);
        const unsigned short* pb = Wr3 + ((size_t)(n0 + lr) * 928 + quad * 8);

        f32x4 acc0 = {0.f, 0.f, 0.f, 0.f};
        f32x4 acc1 = {0.f, 0.f, 0.f, 0.f};
        if (kh == 0) {
#pragma unroll
            for (int kk = 0; kk < 14; kk += 2) {       // kk 0..13
                half8 a0 = load_h8(pa + kk * 32);
                half8 b0 = load_h8(pb + kk * 32);
                acc0 = __builtin_amdgcn_mfma_f32_16x16x32_f16(a0, b0, acc0, 0, 0, 0);
                half8 a1 = load_h8(pa + kk * 32 + 32);
                half8 b1 = load_h8(pb + kk * 32 + 32);
                acc1 = __builtin_amdgcn_mfma_f32_16x16x32_f16(a1, b1, acc1, 0, 0, 0);
            }
        } else {
#pragma unroll
            for (int kk = 14; kk + 1 < 29; kk += 2) {  // kk 14..27
                half8 a0 = load_h8(pa + kk * 32);
                half8 b0 = load_h8(pb + kk * 32);
                acc0 = __builtin_amdgcn_mfma_f32_16x16x32_f16(a0, b0, acc0, 0, 0, 0);
                half8 a1 = load_h8(pa + kk * 32 + 32);
                half8 b1 = load_h8(pb + kk * 32 + 32);
                acc1 = __builtin_amdgcn_mfma_f32_16x16x32_f16(a1, b1, acc1, 0, 0, 0);
            }
            {   // tail kk=28
                half8 a0 = load_h8(pa + 28 * 32);
                half8 b0 = load_h8(pb + 28 * 32);
                acc0 = __builtin_amdgcn_mfma_f32_16x16x32_f16(a0, b0, acc0, 0, 0, 0);
            }
        }
        f32x4 accw = acc0 + acc1;
        if (kh == 1) {
            cld[mt * 64 + lane] = make_float4(accw[0], accw[1], accw[2], accw[3]);
        }
        __syncthreads();
        if (kh == 0) {
            float4 p = cld[mt * 64 + lane];
            int h = n0 + lr;
            if (h < H) {
                float bias = convB[h];
                ct[(size_t)(b * 256 + j0 + quad * 4 + 0) * 200 + h] = f2h(accw[0] + p.x + bias);
                ct[(size_t)(b * 256 + j0 + quad * 4 + 1) * 200 + h] = f2h(accw[1] + p.y + bias);
                ct[(size_t)(b * 256 + j0 + quad * 4 + 2) * 200 + h] = f2h(accw[2] + p.z + bias);
                ct[(size_t)(b * 256 + j0 + quad * 4 + 3) * 200 + h] = f2h(accw[3] + p.w + bias);
            }
        }
    }
    gbar(bar, 1);

    // ================= Stage C: dynamic max pool (512 virtual blocks) =========
    if (bid < 512) {
        int pg = bid & 63;
        int b  = bid >> 6;
        int sub = tid >> 6;
        int lane = tid & 63;
        int p0 = pg * 4 + 1;                           // pivots p0..p0+3

        if (lane < 50) {
            int h = lane << 2;
            const unsigned short* ctb = ct + (size_t)b * S * H + h;
            const unsigned short* gb  = g + h;

            h2 z = {(_Float16)0, (_Float16)0};
            h2 aL0a=z, aL0b=z, aL1a=z, aL1b=z, aL2a=z, aL2b=z, aL3a=z, aL3b=z;
            h2 aR0a=z, aR0b=z, aR1a=z, aR1b=z, aR2a=z, aR2b=z, aR3a=z, aR3b=z;

            if (sub == 0) {                            // j = 0 special (always left)
                uint2 cu = *(const uint2*)ctb;
                h2 ca = u2h2(cu.x), cb = u2h2(cu.y);
                int m = pg * 4;
                if (m + 0 < NI) { uint2 t = *(const uint2*)(c0 + (m+0) * H + h);
                    aL0a = hmax2(aL0a, ca + u2h2(t.x)); aL0b = hmax2(aL0b, cb + u2h2(t.y)); }
                if (m + 1 < NI) { uint2 t = *(const uint2*)(c0 + (m+1) * H + h);
                    aL1a = hmax2(aL1a, ca + u2h2(t.x)); aL1b = hmax2(aL1b, cb + u2h2(t.y)); }
                if (m + 2 < NI) { uint2 t = *(const uint2*)(c0 + (m+2) * H + h);
                    aL2a = hmax2(aL2a, ca + u2h2(t.x)); aL2b = hmax2(aL2b, cb + u2h2(t.y)); }
                if (m + 3 < NI) { uint2 t = *(const uint2*)(c0 + (m+3) * H + h);
                    aL3a = hmax2(aL3a, ca + u2h2(t.x)); aL3b = hmax2(aL3b, cb + u2h2(t.y)); }
            }
            if (sub == 7) {                            // j = 255 special (always right)
                uint2 cu = *(const uint2*)(ctb + (size_t)255 * H);
                h2 ca = u2h2(cu.x), cb = u2h2(cu.y);
                int m = pg * 4;
                if (m + 0 < NI) { uint2 t = *(const uint2*)(c255 + (m+0) * H + h);
                    aR0a = hmax2(aR0a, ca + u2h2(t.x)); aR0b = hmax2(aR0b, cb + u2h2(t.y)); }
                if (m + 1 < NI) { uint2 t = *(const uint2*)(c255 + (m+1) * H + h);
                    aR1a = hmax2(aR1a, ca + u2h2(t.x)); aR1b = hmax2(aR1b, cb + u2h2(t.y)); }
                if (m + 2 < NI) { uint2 t = *(const uint2*)(c255 + (m+2) * H + h);
                    aR2a = hmax2(aR2a, ca + u2h2(t.x)); aR2b = hmax2(aR2b, cb + u2h2(t.y)); }
                if (m + 3 < NI) { uint2 t = *(const uint2*)(c255 + (m+3) * H + h);
                    aR3a = hmax2(aR3a, ca + u2h2(t.x)); aR3b = hmax2(aR3b, cb + u2h2(t.y)); }
            }

            int js = (sub == 0) ? 1 : sub * 32;
            int je = (sub == 7) ? 254 : sub * 32 + 31;

            uint2 gu;
            gu = *(const uint2*)(gb + (size_t)(js - p0 + 256) * H); h2 gr0a = u2h2(gu.x), gr0b = u2h2(gu.y);
            gu = *(const uint2*)(gb + (size_t)(js - p0 + 255) * H); h2 gr1a = u2h2(gu.x), gr1b = u2h2(gu.y);
            gu = *(const uint2*)(gb + (size_t)(js - p0 + 254) * H); h2 gr2a = u2h2(gu.x), gr2b = u2h2(gu.y);
            gu = *(const uint2*)(gb + (size_t)(js - p0 + 253) * H); h2 gr3a = u2h2(gu.x), gr3b = u2h2(gu.y);

            int eL = (je + 1 < p0) ? (je + 1) : p0;        // [js, eL): all-left
            int mS = (js > p0) ? js : p0;                  // [mS, eM): mixed (<=4)
            int eM = (je + 1 < p0 + 4) ? (je + 1) : (p0 + 4);
            int rS = (js > p0 + 4) ? js : (p0 + 4);        // [rS, je]: all-right

#pragma unroll 4
            for (int j = js; j < eL; ++j) {
                uint2 cu = *(const uint2*)(ctb + (size_t)j * H);
                h2 ca = u2h2(cu.x), cb = u2h2(cu.y);
                aL0a = hmax2(aL0a, ca + gr0a); aL0b = hmax2(aL0b, cb + gr0b);
                aL1a = hmax2(aL1a, ca + gr1a); aL1b = hmax2(aL1b, cb + gr1b);
                aL2a = hmax2(aL2a, ca + gr2a); aL2b = hmax2(aL2b, cb + gr2b);
                aL3a = hmax2(aL3a, ca + gr3a); aL3b = hmax2(aL3b, cb + gr3b);
                gr3a = gr2a; gr3b = gr2b; gr2a = gr1a; gr2b = gr1b; gr1a = gr0a; gr1b = gr0b;
                uint2 gn = *(const uint2*)(gb + (size_t)(j + 1 - p0 + 256) * H);
                gr0a = u2h2(gn.x); gr0b = u2h2(gn.y);
            }
            for (int j = mS; j < eM; ++j) {                // <= 4 iterations
                uint2 cu = *(const uint2*)(ctb + (size_t)j * H);
                h2 ca = u2h2(cu.x), cb = u2h2(cu.y);
                h2 v0a = ca + gr0a, v0b = cb + gr0b;
                h2 v1a = ca + gr1a, v1b = cb + gr1b;
                h2 v2a = ca + gr2a, v2b = cb + gr2b;
                h2 v3a = ca + gr3a, v3b = cb + gr3b;
                if (j < p0)     { aL0a = hmax2(aL0a, v0a); aL0b = hmax2(aL0b, v0b); }
                else            { aR0a = hmax2(aR0a, v0a); aR0b = hmax2(aR0b, v0b); }
                if (j < p0 + 1) { aL1a = hmax2(aL1a, v1a); aL1b = hmax2(aL1b, v1b); }
                else            { aR1a = hmax2(aR1a, v1a); aR1b = hmax2(aR1b, v1b); }
                if (j < p0 + 2) { aL2a = hmax2(aL2a, v2a); aL2b = hmax2(aL2b, v2b); }
                else            { aR2a = hmax2(aR2a, v2a); aR2b = hmax2(aR2b, v2b); }
                if (j < p0 + 3) { aL3a = hmax2(aL3a, v3a); aL3b = hmax2(aL3b, v3b); }
                else            { aR3a = hmax2(aR3a, v3a); aR3b = hmax2(aR3b, v3b); }
                gr3a = gr2a; gr3b = gr2b; gr2a = gr1a; gr2b = gr1b; gr1a = gr0a; gr1b = gr0b;
                uint2 gn = *(const uint2*)(gb + (size_t)(j + 1 - p0 + 256) * H);
                gr0a = u2h2(gn.x); gr0b = u2h2(gn.y);
            }
#pragma unroll 4
            for (int j = rS; j <= je; ++j) {
                uint2 cu = *(const uint2*)(ctb + (size_t)j * H);
                h2 ca = u2h2(cu.x), cb = u2h2(cu.y);
                aR0a = hmax2(aR0a, ca + gr0a); aR0b = hmax2(aR0b, cb + gr0b);
                aR1a = hmax2(aR1a, ca + gr1a); aR1b = hmax2(aR1b, cb + gr1b);
                aR2a = hmax2(aR2a, ca + gr2a); aR2b = hmax2(aR2b, cb + gr2b);
                aR3a = hmax2(aR3a, ca + gr3a); aR3b = hmax2(aR3b, cb + gr3b);
                gr3a = gr2a; gr3b = gr2b; gr2a = gr1a; gr2b = gr1b; gr1a = gr0a; gr1b = gr0b;
                uint2 gn = *(const uint2*)(gb + (size_t)(j + 1 - p0 + 256) * H);
                gr0a = u2h2(gn.x); gr0b = u2h2(gn.y);
            }

            uint2* lp = lds2 + (size_t)sub * 400 + lane;
            lp[0]   = make_uint2(h2u(aL0a), h2u(aL0b)); lp[50]  = make_uint2(h2u(aR0a), h2u(aR0b));
            lp[100] = make_uint2(h2u(aL1a), h2u(aL1b)); lp[150] = make_uint2(h2u(aR1a), h2u(aR1b));
            lp[200] = make_uint2(h2u(aL2a), h2u(aL2b)); lp[250] = make_uint2(h2u(aR2a), h2u(aR2b));
            lp[300] = make_uint2(h2u(aL3a), h2u(aL3b)); lp[350] = make_uint2(h2u(aR3a), h2u(aR3b));
        }
        __syncthreads();

        if (tid < 400) {
            int k = tid / 100;
            int r = tid - k * 100;
            int hf = r / 50;
            int ln = r - hf * 50;
            int slot = (k * 2 + hf) * 50 + ln;
            uint2 v = lds2[slot];
            h2 va = u2h2(v.x), vb = u2h2(v.y);
#pragma unroll
            for (int s2 = 1; s2 < 8; s2++) {
                uint2 w = lds2[s2 * 400 + slot];
                va = hmax2(va, u2h2(w.x));
                vb = hmax2(vb, u2h2(w.y));
            }
            int m = pg * 4 + k;
            if (m < NI)
                *(uint2*)(poolf + (size_t)(b * 256 + m + 1) * 416 + hf * 200 + ln * 4)
                    = make_uint2(h2u(va), h2u(vb));
        } else if (tid < 464) {                        // zero K-pad cols 400..415
            int t = tid - 400;
            int k = t >> 4, c = t & 15;
            int m = pg * 4 + k;
            if (m < NI) poolf[(size_t)(b * 256 + m + 1) * 416 + 400 + c] = 0;
        }
    }
    gbar(bar, 2);

    // ================= Stage D: FC GEMM, K-split x4 (192 virtual blocks) ======
    if (bid < 192) {
        int n0 = (bid % 3) * 16;
        int mg = bid / 3;
        int wave = tid >> 6;
        int lane = tid & 63;
        int mt = wave & 1;
        int kp = wave >> 1;
        int quad = lane >> 4;
        int lr = lane & 15;
        int mtile = mg * 2 + mt;
        int b = mtile >> 4;
        int s0 = (mtile & 15) << 4;

        const unsigned short* pa0 = poolf + ((size_t)(b * 256 + s0 + lr) * 416 + quad * 8);
        const unsigned short* pb0 = fcWb + ((size_t)(n0 + lr) * 1344 + quad * 8);
        const unsigned short* pa1 = tokb + ((size_t)(b * 258 + s0 + lr) * 300 + quad * 8);
        const unsigned short* pb1 = fcWb + ((size_t)(n0 + lr) * 1344 + 416 + quad * 8);

        f32x4 acc0 = {0.f, 0.f, 0.f, 0.f};
        f32x4 acc1 = {0.f, 0.f, 0.f, 0.f};
        if (kp == 0) {
#pragma unroll
            for (int u = 0; u + 1 < 11; u += 2) {      // pool u 0..9
                half8 a0 = load_h8(pa0 + u * 32);
                half8 b0 = load_h8(pb0 + u * 32);
                acc0 = __builtin_amdgcn_mfma_f32_16x16x32_f16(a0, b0, acc0, 0, 0, 0);
                half8 a1 = load_h8(pa0 + u * 32 + 32);
                half8 b1 = load_h8(pb0 + u * 32 + 32);
                acc1 = __builtin_amdgcn_mfma_f32_16x16x32_f16(a1, b1, acc1, 0, 0, 0);
            }
            {   // pool tail u=10
                half8 a0 = load_h8(pa0 + 10 * 32);
                half8 b0 = load_h8(pb0 + 10 * 32);
                acc0 = __builtin_amdgcn_mfma_f32_16x16x32_f16(a0, b0, acc0, 0, 0, 0);
            }
        } else if (kp == 1) {
            {   // pool u=11,12
                half8 a0 = load_h8(pa0 + 11 * 32);
                half8 b0 = load_h8(pb0 + 11 * 32);
                acc0 = __builtin_amdgcn_mfma_f32_16x16x32_f16(a0, b0, acc0, 0, 0, 0);
                half8 a1 = load_h8(pa0 + 12 * 32);
                half8 b1 = load_h8(pb0 + 12 * 32);
                acc1 = __builtin_amdgcn_mfma_f32_16x16x32_f16(a1, b1, acc1, 0, 0, 0);
            }
#pragma unroll
            for (int v = 0; v + 1 < 9; v += 2) {       // llf v 0..7
                half8 a0 = load_h8(pa1 + v * 32);
                half8 b0 = load_h8(pb1 + v * 32);
                acc0 = __builtin_amdgcn_mfma_f32_16x16x32_f16(a0, b0, acc0, 0, 0, 0);
                half8 a1 = load_h8(pa1 + v * 32 + 32);
                half8 b1 = load_h8(pb1 + v * 32 + 32);
                acc1 = __builtin_amdgcn_mfma_f32_16x16x32_f16(a1, b1, acc1, 0, 0, 0);
            }
            {   // llf tail v=8
                half8 a0 = load_h8(pa1 + 8 * 32);
                half8 b0 = load_h8(pb1 + 8 * 32);
                acc0 = __builtin_amdgcn_mfma_f32_16x16x32_f16(a0, b0, acc0, 0, 0, 0);
            }
        } else if (kp == 2) {
#pragma unroll
            for (int v = 9; v + 1 < 19; v += 2) {      // llf v 9..18
                half8 a0 = load_h8(pa1 + v * 32);
                half8 b0 = load_h8(pb1 + v * 32);
                acc0 = __builtin_amdgcn_mfma_f32_16x16x32_f16(a0, b0, acc0, 0, 0, 0);
                half8 a1 = load_h8(pa1 + v * 32 + 32);
                half8 b1 = load_h8(pb1 + v * 32 + 32);
                acc1 = __builtin_amdgcn_mfma_f32_16x16x32_f16(a1, b1, acc1, 0, 0, 0);
            }
        } else {
#pragma unroll
            for (int v = 19; v + 1 < 29; v += 2) {     // llf v 19..28
                half8 a0 = load_h8(pa1 + v * 32);
                half8 b0 = load_h8(pb1 + v * 32);
                acc0 = __builtin_amdgcn_mfma_f32_16x16x32_f16(a0, b0, acc0, 0, 0, 0);
                half8 a1 = load_h8(pa1 + v * 32 + 32);
                half8 b1 = load_h8(pb1 + v * 32 + 32);
                acc1 = __builtin_amdgcn_mfma_f32_16x16x32_f16(a1, b1, acc1, 0, 0, 0);
            }
        }
        f32x4 accw = acc0 + acc1;
        if (kp > 0) {
            cld[((kp - 1) * 2 + mt) * 64 + lane] = make_float4(accw[0], accw[1], accw[2], accw[3]);
        }
        __syncthreads();
        if (kp == 0) {
            float4 p1 = cld[(0 * 2 + mt) * 64 + lane];
            float4 p2 = cld[(1 * 2 + mt) * 64 + lane];
            float4 p3 = cld[(2 * 2 + mt) * 64 + lane];
            float r4[4] = {accw[0] + p1.x + p2.x + p3.x,
                           accw[1] + p1.y + p2.y + p3.y,
                           accw[2] + p1.z + p2.z + p3.z,
                           accw[3] + p1.w + p2.w + p3.w};
            int l = n0 + lr;
            if (l < L) {
                float bias = fcB[l];
#pragma unroll
                for (int r = 0; r < 4; r++) {
                    int s = s0 + quad * 4 + r;
                    float val;
                    if (s == 0 || s == S - 1) val = (l == L - 1) ? 1.0f : 0.0f;
                    else                      val = r4[r] + bias;
                    out[(size_t)(b * 256 + s) * L + l] = val;
                }
            }
        }
    }
}

extern "C" void kernel_launch(void* const* d_in, const int* in_sizes, int n_in,
                              void* d_out, int out_size, void* d_ws, size_t ws_size,
                              hipStream_t stream) {
    const int*   ids      = (const int*)d_in[0];
    const float* word_emb = (const float*)d_in[1];
    const float* pf_emb   = (const float*)d_in[2];
    const float* conv_W   = (const float*)d_in[3];
    const float* conv_b   = (const float*)d_in[4];
    const float* fc_W     = (const float*)d_in[5];
    const float* fc_b     = (const float*)d_in[6];
    float* out = (float*)d_out;
    float* ws  = (float*)d_ws;

    unsigned short* tokb  = (unsigned short*)(ws + TOKB_OFF);
    unsigned short* Wr3   = (unsigned short*)(ws + WR3_OFF);
    unsigned short* fcWb  = (unsigned short*)(ws + FCWB_OFF);
    unsigned short* g     = (unsigned short*)(ws + G_OFF);
    unsigned short* c0    = (unsigned short*)(ws + C0_OFF);
    unsigned short* c255  = (unsigned short*)(ws + C255_OFF);
    unsigned short* ct    = (unsigned short*)(ws + CT_OFF);
    unsigned short* poolf = (unsigned short*)(ws + POOLF_OFF);
    unsigned*       bar   = (unsigned*)(ws + BAR_OFF);

    hipMemsetAsync(bar, 0, 3 * 4096, stream);  // zero barrier counters
    k_fused<<<NBLK, 512, 0, stream>>>(ids, word_emb, conv_W, fc_W, pf_emb,
                                      conv_b, fc_b, tokb, Wr3, fcWb, g,
                                      c0, c255, ct, poolf, out, bar);
}

// Round 6
// 199.065 us; speedup vs baseline: 2.6893x; 2.6893x over previous
//
#include <hip/hip_runtime.h>

#define E 300
#define P 5
#define H 200
#define S 256
#define L 34
#define B 8
#define NI 254   // pivot positions i = 1..254
#define NBLK 512 // fused BCD grid: 2 blocks/CU x 256 CU co-resident
#define NGRP 8   // barrier groups of 64 blocks

typedef __attribute__((ext_vector_type(8))) _Float16 half8;
typedef __attribute__((ext_vector_type(2))) _Float16 h2;
typedef __attribute__((ext_vector_type(4))) float f32x4;

// ws layout (float units; all f16 arrays)
#define TOKB_OFF   0            // tokb f16[8][258][300] (+slack)
#define WR3_OFF    309632       // Wr3[208][928] f16
#define FCWB_OFF   406144       // fcWb[48][1344] f16
#define G_OFF      438400       // g f16[512][200]
#define C0_OFF     489600       // c0 f16[254][200]
#define C255_OFF   515000       // c255 f16[254][200]
#define CT_OFF     540400       // ct f16[b][j][h]
#define POOLF_OFF  745200       // poolf f16[b][256][416]
#define BAR_OFF    2000000      // barrier counters: 2 phases x 4KB

__device__ __forceinline__ unsigned short f2h(float f) {
    _Float16 h = (_Float16)f;               // RNE
    unsigned short u; __builtin_memcpy(&u, &h, 2);
    return u;
}
__device__ __forceinline__ h2 u2h2(unsigned u) {
    h2 h; __builtin_memcpy(&h, &u, 4); return h;
}
__device__ __forceinline__ unsigned h2u(h2 h) {
    unsigned u; __builtin_memcpy(&u, &h, 4); return u;
}
__device__ __forceinline__ h2 hmax2(h2 a, h2 b) {
    return __builtin_elementwise_max(a, b);  // v_pk_max_f16
}
__device__ __forceinline__ half8 load_h8(const unsigned short* p) {
    half8 r;
    ((ushort4*)&r)[0] = *(const ushort4*)p;  // rows are 8B-aligned
    ((ushort4*)&r)[1] = *(const ushort4*)(p + 4);
    return r;
}

// k_init block ranges (R4-verified structure)
#define GA_BLOCKS   605   // gather: 154800 items
#define WR3_BLOCKS  754   // Wr3 repack: 193024 items
#define FCW_BLOCKS  252   // fcWb repack: 64512 items
#define PREP_BLOCKS 64    // factored g/c0/c255: 1020 rows x 200 h
#define INIT_BLOCKS (GA_BLOCKS + WR3_BLOCKS + FCW_BLOCKS + PREP_BLOCKS)  // 1675

// Two-level software grid barrier (correctness proven R3/R5). Agent-scope
// ACQ_REL atomics give cross-XCD ordering. Bounded spin = deadlock fuse.
__device__ __forceinline__ void gbar(unsigned* bar, int phase) {
    __syncthreads();
    if (threadIdx.x == 0) {
        unsigned* base = bar + phase * 1024;
        unsigned* c1 = base + (blockIdx.x >> 6) * 16;   // 64B apart
        unsigned* c2 = base + 1008;
        unsigned prev = __hip_atomic_fetch_add(c1, 1u, __ATOMIC_ACQ_REL,
                                               __HIP_MEMORY_SCOPE_AGENT);
        if (prev == 63)
            __hip_atomic_fetch_add(c2, 1u, __ATOMIC_ACQ_REL,
                                   __HIP_MEMORY_SCOPE_AGENT);
        unsigned t = 0;
        while (__hip_atomic_load(c2, __ATOMIC_ACQUIRE,
                                 __HIP_MEMORY_SCOPE_AGENT) < NGRP) {
            __builtin_amdgcn_s_sleep(2);
            if (++t > (1u << 22)) break;   // fuse: fail visibly, never hang
        }
    }
    __syncthreads();
}

// ---------------- A: standalone init (max TLP; R4-verified) ---------------------
__global__ __launch_bounds__(256) void k_init(const int* __restrict__ ids,
                                              const float* __restrict__ we,
                                              const float* __restrict__ convW,
                                              const float* __restrict__ fcW,
                                              const float* __restrict__ pf,
                                              unsigned short* __restrict__ tokb,
                                              unsigned short* __restrict__ Wr3,
                                              unsigned short* __restrict__ fcWb,
                                              unsigned short* __restrict__ g,
                                              unsigned short* __restrict__ c0,
                                              unsigned short* __restrict__ c255) {
    int bx = blockIdx.x;
    if (bx < GA_BLOCKS) {
        // tokb f16[b][258][300], rows 0 & 257 zero
        int idx = bx * 256 + threadIdx.x;
        const int total = B * 258 * 75;
        if (idx >= total) return;
        int row = idx / 75;
        int col = idx - row * 75;
        int b = row / 258;
        int r = row - b * 258;
        float4 v = make_float4(0.f, 0.f, 0.f, 0.f);
        if (r >= 1 && r <= 256) {
            int id = ids[b * S + (r - 1)];
            v = ((const float4*)we)[(size_t)id * 75 + col];
        }
        ushort4 o;
        o.x = f2h(v.x); o.y = f2h(v.y); o.z = f2h(v.z); o.w = f2h(v.w);
        *(ushort4*)(tokb + (size_t)row * 300 + col * 4) = o;
        return;
    }
    if (bx < GA_BLOCKS + WR3_BLOCKS) {               // Wr3: 208x928, Wr3[h][r*300+e]
        int idx = (bx - GA_BLOCKS) * 256 + threadIdx.x;
        if (idx < 193024) {
            int hh = idx / 928, kk = idx - hh * 928;
            float v = 0.f;
            if (hh < H && kk < 900) {
                int r = kk / 300, e = kk - r * 300;
                v = convW[hh * 915 + e * 3 + r];
            }
            Wr3[idx] = f2h(v);
        }
        return;
    }
    if (bx < GA_BLOCKS + WR3_BLOCKS + FCW_BLOCKS) {  // fcWb: 48x1344
        int t = (bx - GA_BLOCKS - WR3_BLOCKS) * 256 + threadIdx.x;
        if (t < 64512) {
            int l = t / 1344, c = t - l * 1344;
            float v = 0.f;
            if (l < L) {
                if (c < 400) v = fcW[l * 1300 + c];
                else if (c >= 416 && c < 1316) v = fcW[l * 1300 + 400 + (c - 416)];
            }
            fcWb[t] = f2h(v);
        }
        return;
    }
    // ---- factored prep: rows r_glob in [0,1020): g(512) | c0(254) | c255(254)
    {
        __shared__ float cwg[200 * 15];              // cwg[h*15 + q*3 + k]
        int tid = threadIdx.x;
        if (tid < 200) {
            const float* src = convW + tid * 915 + 900;  // 15 contiguous f32
#pragma unroll
            for (int i = 0; i < 15; i++) cwg[tid * 15 + i] = src[i];
        }
        __syncthreads();
        if (tid >= 200) return;
        int h = tid;
        int pb = bx - (GA_BLOCKS + WR3_BLOCKS + FCW_BLOCKS);
#pragma unroll 1
        for (int rl = 0; rl < 16; rl++) {
            int rg = pb * 16 + rl;
            if (rg >= 1020) break;
            float a = 0.f;
            if (rg < 512) {                          // g row t2 = rg
                int d = rg - 256;
#pragma unroll
                for (int k = 0; k < 3; k++) {
                    int r = d + k - 1; r = (r < 0) ? -r : r; if (r > 255) r = 255;
#pragma unroll
                    for (int q = 0; q < P; q++)
                        a += cwg[h * 15 + q * 3 + k] * pf[r * P + q];
                }
                g[rg * H + h] = f2h(a);
            } else if (rg < 766) {                   // c0 row m = rg-512, i = m+1
                int m = rg - 512, i = m + 1;
#pragma unroll
                for (int q = 0; q < P; q++) {
                    a += cwg[h * 15 + q * 3 + 1] * pf[i * P + q];
                    a += cwg[h * 15 + q * 3 + 2] * pf[(i - 1) * P + q];
                }
                c0[m * H + h] = f2h(a);
            } else {                                 // c255 row m = rg-766, i = m+1
                int m = rg - 766, i = m + 1;
#pragma unroll
                for (int q = 0; q < P; q++) {
                    a += cwg[h * 15 + q * 3 + 0] * pf[(254 - i) * P + q];
                    a += cwg[h * 15 + q * 3 + 1] * pf[(255 - i) * P + q];
                }
                c255[m * H + h] = f2h(a);
            }
        }
    }
}

// ---------------- BCD fused: conv GEMM -> pool -> FC GEMM, 2 soft barriers -----
// 512 blocks x 512 thr, launch_bounds(512,4): VGPR cap 128 (needs ~64 -> no
// spill, unlike R5's (512,8)=32VGPR+scratch disaster); 2 blocks/CU co-resident
// = 16 waves/CU = stage C's standalone occupancy. LDS union 25.6KB.
__global__ __launch_bounds__(512, 4) void k_bcd(
        const unsigned short* __restrict__ tokb,
        const unsigned short* __restrict__ Wr3,
        const float* __restrict__ convB,
        const unsigned short* __restrict__ g,
        const unsigned short* __restrict__ c0,
        const unsigned short* __restrict__ c255,
        const unsigned short* __restrict__ fcWb,
        const float* __restrict__ fcB,
        unsigned short* __restrict__ ct,
        unsigned short* __restrict__ poolf,
        float* __restrict__ out,
        unsigned* bar) {
    __shared__ __align__(16) unsigned char smem[25600];
    float4* cld = (float4*)smem;               // stages B & D
    uint2*  lds2 = (uint2*)smem;               // stage C

    const int bid = blockIdx.x;
    const int tid = threadIdx.x;

    // ================= Stage B: conv GEMM (416 of 512 blocks) =================
    if (bid < 416) {
        int n0 = (bid % 13) * 16;
        int mg = bid / 13;
        int wave = tid >> 6;
        int lane = tid & 63;
        int mt = wave & 3;
        int kh = wave >> 2;
        int quad = lane >> 4;
        int lr = lane & 15;
        int mtile = mg * 4 + mt;
        int b = mtile >> 4;
        int j0 = (mtile & 15) << 4;

        const unsigned short* pa = tokb + ((size_t)(b * 258 + j0 + lr) * 300 + quad * 8);
        const unsigned short* pb = Wr3 + ((size_t)(n0 + lr) * 928 + quad * 8);

        f32x4 acc0 = {0.f, 0.f, 0.f, 0.f};
        f32x4 acc1 = {0.f, 0.f, 0.f, 0.f};
        if (kh == 0) {
#pragma unroll
            for (int kk = 0; kk < 14; kk += 2) {       // kk 0..13
                half8 a0 = load_h8(pa + kk * 32);
                half8 b0 = load_h8(pb + kk * 32);
                acc0 = __builtin_amdgcn_mfma_f32_16x16x32_f16(a0, b0, acc0, 0, 0, 0);
                half8 a1 = load_h8(pa + kk * 32 + 32);
                half8 b1 = load_h8(pb + kk * 32 + 32);
                acc1 = __builtin_amdgcn_mfma_f32_16x16x32_f16(a1, b1, acc1, 0, 0, 0);
            }
        } else {
#pragma unroll
            for (int kk = 14; kk + 1 < 29; kk += 2) {  // kk 14..27
                half8 a0 = load_h8(pa + kk * 32);
                half8 b0 = load_h8(pb + kk * 32);
                acc0 = __builtin_amdgcn_mfma_f32_16x16x32_f16(a0, b0, acc0, 0, 0, 0);
                half8 a1 = load_h8(pa + kk * 32 + 32);
                half8 b1 = load_h8(pb + kk * 32 + 32);
                acc1 = __builtin_amdgcn_mfma_f32_16x16x32_f16(a1, b1, acc1, 0, 0, 0);
            }
            {   // tail kk=28
                half8 a0 = load_h8(pa + 28 * 32);
                half8 b0 = load_h8(pb + 28 * 32);
                acc0 = __builtin_amdgcn_mfma_f32_16x16x32_f16(a0, b0, acc0, 0, 0, 0);
            }
        }
        f32x4 accw = acc0 + acc1;
        if (kh == 1) {
            cld[mt * 64 + lane] = make_float4(accw[0], accw[1], accw[2], accw[3]);
        }
        __syncthreads();
        if (kh == 0) {
            float4 p = cld[mt * 64 + lane];
            int h = n0 + lr;
            if (h < H) {
                float bias = convB[h];
                ct[(size_t)(b * 256 + j0 + quad * 4 + 0) * 200 + h] = f2h(accw[0] + p.x + bias);
                ct[(size_t)(b * 256 + j0 + quad * 4 + 1) * 200 + h] = f2h(accw[1] + p.y + bias);
                ct[(size_t)(b * 256 + j0 + quad * 4 + 2) * 200 + h] = f2h(accw[2] + p.z + bias);
                ct[(size_t)(b * 256 + j0 + quad * 4 + 3) * 200 + h] = f2h(accw[3] + p.w + bias);
            }
        }
    }
    gbar(bar, 0);

    // ================= Stage C: dynamic max pool (exactly 512 blocks) =========
    {
        int pg = bid & 63;
        int b  = bid >> 6;
        int sub = tid >> 6;
        int lane = tid & 63;
        int p0 = pg * 4 + 1;                           // pivots p0..p0+3

        if (lane < 50) {
            int h = lane << 2;
            const unsigned short* ctb = ct + (size_t)b * S * H + h;
            const unsigned short* gb  = g + h;

            h2 z = {(_Float16)0, (_Float16)0};
            h2 aL0a=z, aL0b=z, aL1a=z, aL1b=z, aL2a=z, aL2b=z, aL3a=z, aL3b=z;
            h2 aR0a=z, aR0b=z, aR1a=z, aR1b=z, aR2a=z, aR2b=z, aR3a=z, aR3b=z;

            if (sub == 0) {                            // j = 0 special (always left)
                uint2 cu = *(const uint2*)ctb;
                h2 ca = u2h2(cu.x), cb = u2h2(cu.y);
                int m = pg * 4;
                if (m + 0 < NI) { uint2 t = *(const uint2*)(c0 + (m+0) * H + h);
                    aL0a = hmax2(aL0a, ca + u2h2(t.x)); aL0b = hmax2(aL0b, cb + u2h2(t.y)); }
                if (m + 1 < NI) { uint2 t = *(const uint2*)(c0 + (m+1) * H + h);
                    aL1a = hmax2(aL1a, ca + u2h2(t.x)); aL1b = hmax2(aL1b, cb + u2h2(t.y)); }
                if (m + 2 < NI) { uint2 t = *(const uint2*)(c0 + (m+2) * H + h);
                    aL2a = hmax2(aL2a, ca + u2h2(t.x)); aL2b = hmax2(aL2b, cb + u2h2(t.y)); }
                if (m + 3 < NI) { uint2 t = *(const uint2*)(c0 + (m+3) * H + h);
                    aL3a = hmax2(aL3a, ca + u2h2(t.x)); aL3b = hmax2(aL3b, cb + u2h2(t.y)); }
            }
            if (sub == 7) {                            // j = 255 special (always right)
                uint2 cu = *(const uint2*)(ctb + (size_t)255 * H);
                h2 ca = u2h2(cu.x), cb = u2h2(cu.y);
                int m = pg * 4;
                if (m + 0 < NI) { uint2 t = *(const uint2*)(c255 + (m+0) * H + h);
                    aR0a = hmax2(aR0a, ca + u2h2(t.x)); aR0b = hmax2(aR0b, cb + u2h2(t.y)); }
                if (m + 1 < NI) { uint2 t = *(const uint2*)(c255 + (m+1) * H + h);
                    aR1a = hmax2(aR1a, ca + u2h2(t.x)); aR1b = hmax2(aR1b, cb + u2h2(t.y)); }
                if (m + 2 < NI) { uint2 t = *(const uint2*)(c255 + (m+2) * H + h);
                    aR2a = hmax2(aR2a, ca + u2h2(t.x)); aR2b = hmax2(aR2b, cb + u2h2(t.y)); }
                if (m + 3 < NI) { uint2 t = *(const uint2*)(c255 + (m+3) * H + h);
                    aR3a = hmax2(aR3a, ca + u2h2(t.x)); aR3b = hmax2(aR3b, cb + u2h2(t.y)); }
            }

            int js = (sub == 0) ? 1 : sub * 32;
            int je = (sub == 7) ? 254 : sub * 32 + 31;

            uint2 gu;
            gu = *(const uint2*)(gb + (size_t)(js - p0 + 256) * H); h2 gr0a = u2h2(gu.x), gr0b = u2h2(gu.y);
            gu = *(const uint2*)(gb + (size_t)(js - p0 + 255) * H); h2 gr1a = u2h2(gu.x), gr1b = u2h2(gu.y);
            gu = *(const uint2*)(gb + (size_t)(js - p0 + 254) * H); h2 gr2a = u2h2(gu.x), gr2b = u2h2(gu.y);
            gu = *(const uint2*)(gb + (size_t)(js - p0 + 253) * H); h2 gr3a = u2h2(gu.x), gr3b = u2h2(gu.y);

            int eL = (je + 1 < p0) ? (je + 1) : p0;        // [js, eL): all-left
            int mS = (js > p0) ? js : p0;                  // [mS, eM): mixed (<=4)
            int eM = (je + 1 < p0 + 4) ? (je + 1) : (p0 + 4);
            int rS = (js > p0 + 4) ? js : (p0 + 4);        // [rS, je]: all-right

#pragma unroll 4
            for (int j = js; j < eL; ++j) {
                uint2 cu = *(const uint2*)(ctb + (size_t)j * H);
                h2 ca = u2h2(cu.x), cb = u2h2(cu.y);
                aL0a = hmax2(aL0a, ca + gr0a); aL0b = hmax2(aL0b, cb + gr0b);
                aL1a = hmax2(aL1a, ca + gr1a); aL1b = hmax2(aL1b, cb + gr1b);
                aL2a = hmax2(aL2a, ca + gr2a); aL2b = hmax2(aL2b, cb + gr2b);
                aL3a = hmax2(aL3a, ca + gr3a); aL3b = hmax2(aL3b, cb + gr3b);
                gr3a = gr2a; gr3b = gr2b; gr2a = gr1a; gr2b = gr1b; gr1a = gr0a; gr1b = gr0b;
                uint2 gn = *(const uint2*)(gb + (size_t)(j + 1 - p0 + 256) * H);
                gr0a = u2h2(gn.x); gr0b = u2h2(gn.y);
            }
            for (int j = mS; j < eM; ++j) {                // <= 4 iterations
                uint2 cu = *(const uint2*)(ctb + (size_t)j * H);
                h2 ca = u2h2(cu.x), cb = u2h2(cu.y);
                h2 v0a = ca + gr0a, v0b = cb + gr0b;
                h2 v1a = ca + gr1a, v1b = cb + gr1b;
                h2 v2a = ca + gr2a, v2b = cb + gr2b;
                h2 v3a = ca + gr3a, v3b = cb + gr3b;
                if (j < p0)     { aL0a = hmax2(aL0a, v0a); aL0b = hmax2(aL0b, v0b); }
                else            { aR0a = hmax2(aR0a, v0a); aR0b = hmax2(aR0b, v0b); }
                if (j < p0 + 1) { aL1a = hmax2(aL1a, v1a); aL1b = hmax2(aL1b, v1b); }
                else            { aR1a = hmax2(aR1a, v1a); aR1b = hmax2(aR1b, v1b); }
                if (j < p0 + 2) { aL2a = hmax2(aL2a, v2a); aL2b = hmax2(aL2b, v2b); }
                else            { aR2a = hmax2(aR2a, v2a); aR2b = hmax2(aR2b, v2b); }
                if (j < p0 + 3) { aL3a = hmax2(aL3a, v3a); aL3b = hmax2(aL3b, v3b); }
                else            { aR3a = hmax2(aR3a, v3a); aR3b = hmax2(aR3b, v3b); }
                gr3a = gr2a; gr3b = gr2b; gr2a = gr1a; gr2b = gr1b; gr1a = gr0a; gr1b = gr0b;
                uint2 gn = *(const uint2*)(gb + (size_t)(j + 1 - p0 + 256) * H);
                gr0a = u2h2(gn.x); gr0b = u2h2(gn.y);
            }
#pragma unroll 4
            for (int j = rS; j <= je; ++j) {
                uint2 cu = *(const uint2*)(ctb + (size_t)j * H);
                h2 ca = u2h2(cu.x), cb = u2h2(cu.y);
                aR0a = hmax2(aR0a, ca + gr0a); aR0b = hmax2(aR0b, cb + gr0b);
                aR1a = hmax2(aR1a, ca + gr1a); aR1b = hmax2(aR1b, cb + gr1b);
                aR2a = hmax2(aR2a, ca + gr2a); aR2b = hmax2(aR2b, cb + gr2b);
                aR3a = hmax2(aR3a, ca + gr3a); aR3b = hmax2(aR3b, cb + gr3b);
                gr3a = gr2a; gr3b = gr2b; gr2a = gr1a; gr2b = gr1b; gr1a = gr0a; gr1b = gr0b;
                uint2 gn = *(const uint2*)(gb + (size_t)(j + 1 - p0 + 256) * H);
                gr0a = u2h2(gn.x); gr0b = u2h2(gn.y);
            }

            uint2* lp = lds2 + (size_t)sub * 400 + lane;
            lp[0]   = make_uint2(h2u(aL0a), h2u(aL0b)); lp[50]  = make_uint2(h2u(aR0a), h2u(aR0b));
            lp[100] = make_uint2(h2u(aL1a), h2u(aL1b)); lp[150] = make_uint2(h2u(aR1a), h2u(aR1b));
            lp[200] = make_uint2(h2u(aL2a), h2u(aL2b)); lp[250] = make_uint2(h2u(aR2a), h2u(aR2b));
            lp[300] = make_uint2(h2u(aL3a), h2u(aL3b)); lp[350] = make_uint2(h2u(aR3a), h2u(aR3b));
        }
        __syncthreads();

        if (tid < 400) {
            int k = tid / 100;
            int r = tid - k * 100;
            int hf = r / 50;
            int ln = r - hf * 50;
            int slot = (k * 2 + hf) * 50 + ln;
            uint2 v = lds2[slot];
            h2 va = u2h2(v.x), vb = u2h2(v.y);
#pragma unroll
            for (int s2 = 1; s2 < 8; s2++) {
                uint2 w = lds2[s2 * 400 + slot];
                va = hmax2(va, u2h2(w.x));
                vb = hmax2(vb, u2h2(w.y));
            }
            int m = pg * 4 + k;
            if (m < NI)
                *(uint2*)(poolf + (size_t)(b * 256 + m + 1) * 416 + hf * 200 + ln * 4)
                    = make_uint2(h2u(va), h2u(vb));
        } else if (tid < 464) {                        // zero K-pad cols 400..415
            int t = tid - 400;
            int k = t >> 4, c = t & 15;
            int m = pg * 4 + k;
            if (m < NI) poolf[(size_t)(b * 256 + m + 1) * 416 + 400 + c] = 0;
        }
    }
    gbar(bar, 1);

    // ================= Stage D: FC GEMM, K-split x4 (192 of 512 blocks) =======
    if (bid < 192) {
        int n0 = (bid % 3) * 16;
        int mg = bid / 3;
        int wave = tid >> 6;
        int lane = tid & 63;
        int mt = wave & 1;
        int kp = wave >> 1;
        int quad = lane >> 4;
        int lr = lane & 15;
        int mtile = mg * 2 + mt;
        int b = mtile >> 4;
        int s0 = (mtile & 15) << 4;

        const unsigned short* pa0 = poolf + ((size_t)(b * 256 + s0 + lr) * 416 + quad * 8);
        const unsigned short* pb0 = fcWb + ((size_t)(n0 + lr) * 1344 + quad * 8);
        const unsigned short* pa1 = tokb + ((size_t)(b * 258 + s0 + lr) * 300 + quad * 8);
        const unsigned short* pb1 = fcWb + ((size_t)(n0 + lr) * 1344 + 416 + quad * 8);

        f32x4 acc0 = {0.f, 0.f, 0.f, 0.f};
        f32x4 acc1 = {0.f, 0.f, 0.f, 0.f};
        if (kp == 0) {
#pragma unroll
            for (int u = 0; u + 1 < 11; u += 2) {      // pool u 0..9
                half8 a0 = load_h8(pa0 + u * 32);
                half8 b0 = load_h8(pb0 + u * 32);
                acc0 = __builtin_amdgcn_mfma_f32_16x16x32_f16(a0, b0, acc0, 0, 0, 0);
                half8 a1 = load_h8(pa0 + u * 32 + 32);
                half8 b1 = load_h8(pb0 + u * 32 + 32);
                acc1 = __builtin_amdgcn_mfma_f32_16x16x32_f16(a1, b1, acc1, 0, 0, 0);
            }
            {   // pool tail u=10
                half8 a0 = load_h8(pa0 + 10 * 32);
                half8 b0 = load_h8(pb0 + 10 * 32);
                acc0 = __builtin_amdgcn_mfma_f32_16x16x32_f16(a0, b0, acc0, 0, 0, 0);
            }
        } else if (kp == 1) {
            {   // pool u=11,12
                half8 a0 = load_h8(pa0 + 11 * 32);
                half8 b0 = load_h8(pb0 + 11 * 32);
                acc0 = __builtin_amdgcn_mfma_f32_16x16x32_f16(a0, b0, acc0, 0, 0, 0);
                half8 a1 = load_h8(pa0 + 12 * 32);
                half8 b1 = load_h8(pb0 + 12 * 32);
                acc1 = __builtin_amdgcn_mfma_f32_16x16x32_f16(a1, b1, acc1, 0, 0, 0);
            }
#pragma unroll
            for (int v = 0; v + 1 < 9; v += 2) {       // llf v 0..7
                half8 a0 = load_h8(pa1 + v * 32);
                half8 b0 = load_h8(pb1 + v * 32);
                acc0 = __builtin_amdgcn_mfma_f32_16x16x32_f16(a0, b0, acc0, 0, 0, 0);
                half8 a1 = load_h8(pa1 + v * 32 + 32);
                half8 b1 = load_h8(pb1 + v * 32 + 32);
                acc1 = __builtin_amdgcn_mfma_f32_16x16x32_f16(a1, b1, acc1, 0, 0, 0);
            }
            {   // llf tail v=8
                half8 a0 = load_h8(pa1 + 8 * 32);
                half8 b0 = load_h8(pb1 + 8 * 32);
                acc0 = __builtin_amdgcn_mfma_f32_16x16x32_f16(a0, b0, acc0, 0, 0, 0);
            }
        } else if (kp == 2) {
#pragma unroll
            for (int v = 9; v + 1 < 19; v += 2) {      // llf v 9..18
                half8 a0 = load_h8(pa1 + v * 32);
                half8 b0 = load_h8(pb1 + v * 32);
                acc0 = __builtin_amdgcn_mfma_f32_16x16x32_f16(a0, b0, acc0, 0, 0, 0);
                half8 a1 = load_h8(pa1 + v * 32 + 32);
                half8 b1 = load_h8(pb1 + v * 32 + 32);
                acc1 = __builtin_amdgcn_mfma_f32_16x16x32_f16(a1, b1, acc1, 0, 0, 0);
            }
        } else {
#pragma unroll
            for (int v = 19; v + 1 < 29; v += 2) {     // llf v 19..28
                half8 a0 = load_h8(pa1 + v * 32);
                half8 b0 = load_h8(pb1 + v * 32);
                acc0 = __builtin_amdgcn_mfma_f32_16x16x32_f16(a0, b0, acc0, 0, 0, 0);
                half8 a1 = load_h8(pa1 + v * 32 + 32);
                half8 b1 = load_h8(pb1 + v * 32 + 32);
                acc1 = __builtin_amdgcn_mfma_f32_16x16x32_f16(a1, b1, acc1, 0, 0, 0);
            }
        }
        f32x4 accw = acc0 + acc1;
        if (kp > 0) {
            cld[((kp - 1) * 2 + mt) * 64 + lane] = make_float4(accw[0], accw[1], accw[2], accw[3]);
        }
        __syncthreads();
        if (kp == 0) {
            float4 p1 = cld[(0 * 2 + mt) * 64 + lane];
            float4 p2 = cld[(1 * 2 + mt) * 64 + lane];
            float4 p3 = cld[(2 * 2 + mt) * 64 + lane];
            float r4[4] = {accw[0] + p1.x + p2.x + p3.x,
                           accw[1] + p1.y + p2.y + p3.y,
                           accw[2] + p1.z + p2.z + p3.z,
                           accw[3] + p1.w + p2.w + p3.w};
            int l = n0 + lr;
            if (l < L) {
                float bias = fcB[l];
#pragma unroll
                for (int r = 0; r < 4; r++) {
                    int s = s0 + quad * 4 + r;
                    float val;
                    if (s == 0 || s == S - 1) val = (l == L - 1) ? 1.0f : 0.0f;
                    else                      val = r4[r] + bias;
                    out[(size_t)(b * 256 + s) * L + l] = val;
                }
            }
        }
    }
}

extern "C" void kernel_launch(void* const* d_in, const int* in_sizes, int n_in,
                              void* d_out, int out_size, void* d_ws, size_t ws_size,
                              hipStream_t stream) {
    const int*   ids      = (const int*)d_in[0];
    const float* word_emb = (const float*)d_in[1];
    const float* pf_emb   = (const float*)d_in[2];
    const float* conv_W   = (const float*)d_in[3];
    const float* conv_b   = (const float*)d_in[4];
    const float* fc_W     = (const float*)d_in[5];
    const float* fc_b     = (const float*)d_in[6];
    float* out = (float*)d_out;
    float* ws  = (float*)d_ws;

    unsigned short* tokb  = (unsigned short*)(ws + TOKB_OFF);
    unsigned short* Wr3   = (unsigned short*)(ws + WR3_OFF);
    unsigned short* fcWb  = (unsigned short*)(ws + FCWB_OFF);
    unsigned short* g     = (unsigned short*)(ws + G_OFF);
    unsigned short* c0    = (unsigned short*)(ws + C0_OFF);
    unsigned short* c255  = (unsigned short*)(ws + C255_OFF);
    unsigned short* ct    = (unsigned short*)(ws + CT_OFF);
    unsigned short* poolf = (unsigned short*)(ws + POOLF_OFF);
    unsigned*       bar   = (unsigned*)(ws + BAR_OFF);

    hipMemsetAsync(bar, 0, 2 * 4096, stream);  // zero barrier counters
    k_init<<<INIT_BLOCKS, 256, 0, stream>>>(ids, word_emb, conv_W, fc_W,
                                            pf_emb, tokb, Wr3, fcWb,
                                            g, c0, c255);
    k_bcd<<<NBLK, 512, 0, stream>>>(tokb, Wr3, conv_b, g, c0, c255,
                                    fcWb, fc_b, ct, poolf, out, bar);
}

// Round 7
// 113.578 us; speedup vs baseline: 4.7134x; 1.7527x over previous
//
#include <hip/hip_runtime.h>

#define E 300
#define P 5
#define H 200
#define S 256
#define L 34
#define B 8
#define NI 254   // pivot positions i = 1..254

typedef __attribute__((ext_vector_type(8))) _Float16 half8;
typedef __attribute__((ext_vector_type(2))) _Float16 h2;
typedef __attribute__((ext_vector_type(4))) float f32x4;

// ws layout (float units; all f16 arrays)
#define TOKB_OFF   0            // tokb f16[8][258][300] (+slack)
#define WR3_OFF    309632       // Wr3[208][928] f16
#define FCWB_OFF   406144       // fcWb[48][1344] f16
#define G_OFF      438400       // g f16[512][200]
#define C0_OFF     489600       // c0 f16[254][200]
#define C255_OFF   515000       // c255 f16[254][200]
#define CT_OFF     540400       // ct f16[b][j][h]
#define POOLF_OFF  745200       // poolf f16[b][256][416]

__device__ __forceinline__ unsigned short f2h(float f) {
    _Float16 h = (_Float16)f;               // RNE
    unsigned short u; __builtin_memcpy(&u, &h, 2);
    return u;
}
__device__ __forceinline__ h2 u2h2(unsigned u) {
    h2 h; __builtin_memcpy(&h, &u, 4); return h;
}
__device__ __forceinline__ unsigned h2u(h2 h) {
    unsigned u; __builtin_memcpy(&u, &h, 4); return u;
}
__device__ __forceinline__ h2 hmax2(h2 a, h2 b) {
    return __builtin_elementwise_max(a, b);  // v_pk_max_f16
}
__device__ __forceinline__ half8 load_h8(const unsigned short* p) {
    half8 r;
    ((ushort4*)&r)[0] = *(const ushort4*)p;  // rows are 8B-aligned
    ((ushort4*)&r)[1] = *(const ushort4*)(p + 4);
    return r;
}

// k_init: gather + Wr3 only (tail sections moved into k_conv dispatch)
#define GA_BLOCKS   605   // gather: 154800 items
#define WR3_BLOCKS  754   // Wr3 repack: 193024 items
#define INIT_BLOCKS (GA_BLOCKS + WR3_BLOCKS)   // 1359

// k_conv dispatch: 416 conv blocks + 126 fcWb blocks + 64 prep blocks
#define CONV_BLOCKS 416
#define FCW_BLOCKS  126   // fcWb repack: 64512 items @512 thr
#define PREP_BLOCKS 64    // factored g/c0/c255: 1020 rows x 200 h
#define CONVD_BLOCKS (CONV_BLOCKS + FCW_BLOCKS + PREP_BLOCKS)  // 606

// ---------------- A: init = embedding gather + Wr3 repack (conv deps only) -----
__global__ __launch_bounds__(256) void k_init(const int* __restrict__ ids,
                                              const float* __restrict__ we,
                                              const float* __restrict__ convW,
                                              unsigned short* __restrict__ tokb,
                                              unsigned short* __restrict__ Wr3) {
    int bx = blockIdx.x;
    if (bx < GA_BLOCKS) {
        // tokb f16[b][258][300], rows 0 & 257 zero
        int idx = bx * 256 + threadIdx.x;
        const int total = B * 258 * 75;
        if (idx >= total) return;
        int row = idx / 75;
        int col = idx - row * 75;
        int b = row / 258;
        int r = row - b * 258;
        float4 v = make_float4(0.f, 0.f, 0.f, 0.f);
        if (r >= 1 && r <= 256) {
            int id = ids[b * S + (r - 1)];
            v = ((const float4*)we)[(size_t)id * 75 + col];
        }
        ushort4 o;
        o.x = f2h(v.x); o.y = f2h(v.y); o.z = f2h(v.z); o.w = f2h(v.w);
        *(ushort4*)(tokb + (size_t)row * 300 + col * 4) = o;
        return;
    }
    {   // Wr3: 208x928, Wr3[h][r*300+e]
        int idx = (bx - GA_BLOCKS) * 256 + threadIdx.x;
        if (idx < 193024) {
            int hh = idx / 928, kk = idx - hh * 928;
            float v = 0.f;
            if (hh < H && kk < 900) {
                int r = kk / 300, e = kk - r * 300;
                v = convW[hh * 915 + e * 3 + r];
            }
            Wr3[idx] = f2h(v);
        }
    }
}

// ---------------- B: conv GEMM + (riding along) fcWb repack + pf prep ----------
// conv: M=2048 (b,j), N=208, K=928. 8 waves = 4 mtiles x 2 K-halves; LDS combine.
// Blocks 416..541: fcWb repack (needed only by k_fc). Blocks 542..605: factored
// g/c0/c255 prep, register-resident cw[15] (needed only by k_pool). Stream
// order guarantees completion before their consumers launch. No sync needed.
__global__ __launch_bounds__(512) void k_conv(const unsigned short* __restrict__ tokb,
                                              const unsigned short* __restrict__ Wr3,
                                              const float* __restrict__ convB,
                                              const float* __restrict__ convW,
                                              const float* __restrict__ fcW,
                                              const float* __restrict__ pf,
                                              unsigned short* __restrict__ ct,
                                              unsigned short* __restrict__ fcWb,
                                              unsigned short* __restrict__ g,
                                              unsigned short* __restrict__ c0,
                                              unsigned short* __restrict__ c255) {
    __shared__ float4 cld[4 * 64];                 // conv blocks: [mt][lane] 4 KB
    int vb = blockIdx.x;
    int tid = threadIdx.x;

    if (vb >= CONV_BLOCKS) {
        int xb = vb - CONV_BLOCKS;
        if (xb < FCW_BLOCKS) {                     // fcWb: 48x1344
            int t = xb * 512 + tid;
            if (t < 64512) {
                int l = t / 1344, c = t - l * 1344;
                float v = 0.f;
                if (l < L) {
                    if (c < 400) v = fcW[l * 1300 + c];
                    else if (c >= 416 && c < 1316) v = fcW[l * 1300 + 400 + (c - 416)];
                }
                fcWb[t] = f2h(v);
            }
        } else if (tid < 200) {
            // factored prep: rows rg in [0,1020): g(512) | c0(254) | c255(254)
            int h = tid;
            float cw[15];
            const float* src = convW + h * 915 + 900;  // 15 contiguous f32
#pragma unroll
            for (int i = 0; i < 15; i++) cw[i] = src[i];
            int pb = xb - FCW_BLOCKS;
#pragma unroll 1
            for (int rl = 0; rl < 16; rl++) {
                int rg = pb * 16 + rl;
                if (rg >= 1020) break;
                float a = 0.f;
                if (rg < 512) {                          // g row t2 = rg
                    int d = rg - 256;
#pragma unroll
                    for (int k = 0; k < 3; k++) {
                        int r = d + k - 1; r = (r < 0) ? -r : r; if (r > 255) r = 255;
#pragma unroll
                        for (int q = 0; q < P; q++)
                            a += cw[q * 3 + k] * pf[r * P + q];
                    }
                    g[rg * H + h] = f2h(a);
                } else if (rg < 766) {                   // c0 row m = rg-512, i = m+1
                    int m = rg - 512, i = m + 1;
#pragma unroll
                    for (int q = 0; q < P; q++) {
                        a += cw[q * 3 + 1] * pf[i * P + q];
                        a += cw[q * 3 + 2] * pf[(i - 1) * P + q];
                    }
                    c0[m * H + h] = f2h(a);
                } else {                                 // c255 row m = rg-766, i = m+1
                    int m = rg - 766, i = m + 1;
#pragma unroll
                    for (int q = 0; q < P; q++) {
                        a += cw[q * 3 + 0] * pf[(254 - i) * P + q];
                        a += cw[q * 3 + 1] * pf[(255 - i) * P + q];
                    }
                    c255[m * H + h] = f2h(a);
                }
            }
        }
        return;
    }

    // ---- conv GEMM block (mapping verified R3/R5/R6) ----
    int n0 = (vb % 13) * 16;
    int mg = vb / 13;
    int wave = tid >> 6;
    int lane = tid & 63;
    int mt = wave & 3;
    int kh = wave >> 2;
    int quad = lane >> 4;
    int lr = lane & 15;
    int mtile = mg * 4 + mt;
    int b = mtile >> 4;
    int j0 = (mtile & 15) << 4;

    const unsigned short* pa = tokb + ((size_t)(b * 258 + j0 + lr) * 300 + quad * 8);
    const unsigned short* pb = Wr3 + ((size_t)(n0 + lr) * 928 + quad * 8);

    f32x4 acc0 = {0.f, 0.f, 0.f, 0.f};
    f32x4 acc1 = {0.f, 0.f, 0.f, 0.f};
    if (kh == 0) {
#pragma unroll
        for (int kk = 0; kk < 14; kk += 2) {       // kk 0..13
            half8 a0 = load_h8(pa + kk * 32);
            half8 b0 = load_h8(pb + kk * 32);
            acc0 = __builtin_amdgcn_mfma_f32_16x16x32_f16(a0, b0, acc0, 0, 0, 0);
            half8 a1 = load_h8(pa + kk * 32 + 32);
            half8 b1 = load_h8(pb + kk * 32 + 32);
            acc1 = __builtin_amdgcn_mfma_f32_16x16x32_f16(a1, b1, acc1, 0, 0, 0);
        }
    } else {
#pragma unroll
        for (int kk = 14; kk + 1 < 29; kk += 2) {  // kk 14..27
            half8 a0 = load_h8(pa + kk * 32);
            half8 b0 = load_h8(pb + kk * 32);
            acc0 = __builtin_amdgcn_mfma_f32_16x16x32_f16(a0, b0, acc0, 0, 0, 0);
            half8 a1 = load_h8(pa + kk * 32 + 32);
            half8 b1 = load_h8(pb + kk * 32 + 32);
            acc1 = __builtin_amdgcn_mfma_f32_16x16x32_f16(a1, b1, acc1, 0, 0, 0);
        }
        {   // tail kk=28
            half8 a0 = load_h8(pa + 28 * 32);
            half8 b0 = load_h8(pb + 28 * 32);
            acc0 = __builtin_amdgcn_mfma_f32_16x16x32_f16(a0, b0, acc0, 0, 0, 0);
        }
    }
    f32x4 accw = acc0 + acc1;
    if (kh == 1) {
        cld[mt * 64 + lane] = make_float4(accw[0], accw[1], accw[2], accw[3]);
    }
    __syncthreads();
    if (kh == 0) {
        float4 p = cld[mt * 64 + lane];
        int h = n0 + lr;
        if (h < H) {
            float bias = convB[h];
            ct[(size_t)(b * 256 + j0 + quad * 4 + 0) * 200 + h] = f2h(accw[0] + p.x + bias);
            ct[(size_t)(b * 256 + j0 + quad * 4 + 1) * 200 + h] = f2h(accw[1] + p.y + bias);
            ct[(size_t)(b * 256 + j0 + quad * 4 + 2) * 200 + h] = f2h(accw[2] + p.z + bias);
            ct[(size_t)(b * 256 + j0 + quad * 4 + 3) * 200 + h] = f2h(accw[3] + p.w + bias);
        }
    }
}

// ---------------- C: dynamic max pool, packed-f16 VALU -> poolf f16[b][256][416] ----
// grid (64 pg, 8 b); 512 thr = 8 j-subs x 64 lanes (50 active, h=4*lane), 32 j each.
__global__ __launch_bounds__(512) void k_poolA(const unsigned short* __restrict__ ct,
                                               const unsigned short* __restrict__ g,
                                               const unsigned short* __restrict__ c0,
                                               const unsigned short* __restrict__ c255,
                                               unsigned short* __restrict__ poolf) {
    __shared__ uint2 lds2[8 * 4 * 2 * 50];         // [sub][k][lr][lane], 4 f16 each; 25.6 KB
    int pg = blockIdx.x;
    int b  = blockIdx.y;
    int tid = threadIdx.x;
    int sub = tid >> 6;
    int lane = tid & 63;
    int p0 = pg * 4 + 1;                           // pivots p0..p0+3

    if (lane < 50) {
        int h = lane << 2;
        const unsigned short* ctb = ct + (size_t)b * S * H + h;
        const unsigned short* gb  = g + h;

        h2 z = {(_Float16)0, (_Float16)0};
        h2 aL0a=z, aL0b=z, aL1a=z, aL1b=z, aL2a=z, aL2b=z, aL3a=z, aL3b=z;
        h2 aR0a=z, aR0b=z, aR1a=z, aR1b=z, aR2a=z, aR2b=z, aR3a=z, aR3b=z;

        if (sub == 0) {                            // j = 0 special (always left)
            uint2 cu = *(const uint2*)ctb;
            h2 ca = u2h2(cu.x), cb = u2h2(cu.y);
            int m = pg * 4;
            if (m + 0 < NI) { uint2 t = *(const uint2*)(c0 + (m+0) * H + h);
                aL0a = hmax2(aL0a, ca + u2h2(t.x)); aL0b = hmax2(aL0b, cb + u2h2(t.y)); }
            if (m + 1 < NI) { uint2 t = *(const uint2*)(c0 + (m+1) * H + h);
                aL1a = hmax2(aL1a, ca + u2h2(t.x)); aL1b = hmax2(aL1b, cb + u2h2(t.y)); }
            if (m + 2 < NI) { uint2 t = *(const uint2*)(c0 + (m+2) * H + h);
                aL2a = hmax2(aL2a, ca + u2h2(t.x)); aL2b = hmax2(aL2b, cb + u2h2(t.y)); }
            if (m + 3 < NI) { uint2 t = *(const uint2*)(c0 + (m+3) * H + h);
                aL3a = hmax2(aL3a, ca + u2h2(t.x)); aL3b = hmax2(aL3b, cb + u2h2(t.y)); }
        }
        if (sub == 7) {                            // j = 255 special (always right)
            uint2 cu = *(const uint2*)(ctb + (size_t)255 * H);
            h2 ca = u2h2(cu.x), cb = u2h2(cu.y);
            int m = pg * 4;
            if (m + 0 < NI) { uint2 t = *(const uint2*)(c255 + (m+0) * H + h);
                aR0a = hmax2(aR0a, ca + u2h2(t.x)); aR0b = hmax2(aR0b, cb + u2h2(t.y)); }
            if (m + 1 < NI) { uint2 t = *(const uint2*)(c255 + (m+1) * H + h);
                aR1a = hmax2(aR1a, ca + u2h2(t.x)); aR1b = hmax2(aR1b, cb + u2h2(t.y)); }
            if (m + 2 < NI) { uint2 t = *(const uint2*)(c255 + (m+2) * H + h);
                aR2a = hmax2(aR2a, ca + u2h2(t.x)); aR2b = hmax2(aR2b, cb + u2h2(t.y)); }
            if (m + 3 < NI) { uint2 t = *(const uint2*)(c255 + (m+3) * H + h);
                aR3a = hmax2(aR3a, ca + u2h2(t.x)); aR3b = hmax2(aR3b, cb + u2h2(t.y)); }
        }

        int js = (sub == 0) ? 1 : sub * 32;
        int je = (sub == 7) ? 254 : sub * 32 + 31;

        uint2 gu;
        gu = *(const uint2*)(gb + (size_t)(js - p0 + 256) * H); h2 gr0a = u2h2(gu.x), gr0b = u2h2(gu.y);
        gu = *(const uint2*)(gb + (size_t)(js - p0 + 255) * H); h2 gr1a = u2h2(gu.x), gr1b = u2h2(gu.y);
        gu = *(const uint2*)(gb + (size_t)(js - p0 + 254) * H); h2 gr2a = u2h2(gu.x), gr2b = u2h2(gu.y);
        gu = *(const uint2*)(gb + (size_t)(js - p0 + 253) * H); h2 gr3a = u2h2(gu.x), gr3b = u2h2(gu.y);

        int eL = (je + 1 < p0) ? (je + 1) : p0;        // [js, eL): all-left
        int mS = (js > p0) ? js : p0;                  // [mS, eM): mixed (<=4)
        int eM = (je + 1 < p0 + 4) ? (je + 1) : (p0 + 4);
        int rS = (js > p0 + 4) ? js : (p0 + 4);        // [rS, je]: all-right

#pragma unroll 4
        for (int j = js; j < eL; ++j) {
            uint2 cu = *(const uint2*)(ctb + (size_t)j * H);
            h2 ca = u2h2(cu.x), cb = u2h2(cu.y);
            aL0a = hmax2(aL0a, ca + gr0a); aL0b = hmax2(aL0b, cb + gr0b);
            aL1a = hmax2(aL1a, ca + gr1a); aL1b = hmax2(aL1b, cb + gr1b);
            aL2a = hmax2(aL2a, ca + gr2a); aL2b = hmax2(aL2b, cb + gr2b);
            aL3a = hmax2(aL3a, ca + gr3a); aL3b = hmax2(aL3b, cb + gr3b);
            gr3a = gr2a; gr3b = gr2b; gr2a = gr1a; gr2b = gr1b; gr1a = gr0a; gr1b = gr0b;
            uint2 gn = *(const uint2*)(gb + (size_t)(j + 1 - p0 + 256) * H);
            gr0a = u2h2(gn.x); gr0b = u2h2(gn.y);
        }
        for (int j = mS; j < eM; ++j) {                // <= 4 iterations
            uint2 cu = *(const uint2*)(ctb + (size_t)j * H);
            h2 ca = u2h2(cu.x), cb = u2h2(cu.y);
            h2 v0a = ca + gr0a, v0b = cb + gr0b;
            h2 v1a = ca + gr1a, v1b = cb + gr1b;
            h2 v2a = ca + gr2a, v2b = cb + gr2b;
            h2 v3a = ca + gr3a, v3b = cb + gr3b;
            if (j < p0)     { aL0a = hmax2(aL0a, v0a); aL0b = hmax2(aL0b, v0b); }
            else            { aR0a = hmax2(aR0a, v0a); aR0b = hmax2(aR0b, v0b); }
            if (j < p0 + 1) { aL1a = hmax2(aL1a, v1a); aL1b = hmax2(aL1b, v1b); }
            else            { aR1a = hmax2(aR1a, v1a); aR1b = hmax2(aR1b, v1b); }
            if (j < p0 + 2) { aL2a = hmax2(aL2a, v2a); aL2b = hmax2(aL2b, v2b); }
            else            { aR2a = hmax2(aR2a, v2a); aR2b = hmax2(aR2b, v2b); }
            if (j < p0 + 3) { aL3a = hmax2(aL3a, v3a); aL3b = hmax2(aL3b, v3b); }
            else            { aR3a = hmax2(aR3a, v3a); aR3b = hmax2(aR3b, v3b); }
            gr3a = gr2a; gr3b = gr2b; gr2a = gr1a; gr2b = gr1b; gr1a = gr0a; gr1b = gr0b;
            uint2 gn = *(const uint2*)(gb + (size_t)(j + 1 - p0 + 256) * H);
            gr0a = u2h2(gn.x); gr0b = u2h2(gn.y);
        }
#pragma unroll 4
        for (int j = rS; j <= je; ++j) {
            uint2 cu = *(const uint2*)(ctb + (size_t)j * H);
            h2 ca = u2h2(cu.x), cb = u2h2(cu.y);
            aR0a = hmax2(aR0a, ca + gr0a); aR0b = hmax2(aR0b, cb + gr0b);
            aR1a = hmax2(aR1a, ca + gr1a); aR1b = hmax2(aR1b, cb + gr1b);
            aR2a = hmax2(aR2a, ca + gr2a); aR2b = hmax2(aR2b, cb + gr2b);
            aR3a = hmax2(aR3a, ca + gr3a); aR3b = hmax2(aR3b, cb + gr3b);
            gr3a = gr2a; gr3b = gr2b; gr2a = gr1a; gr2b = gr1b; gr1a = gr0a; gr1b = gr0b;
            uint2 gn = *(const uint2*)(gb + (size_t)(j + 1 - p0 + 256) * H);
            gr0a = u2h2(gn.x); gr0b = u2h2(gn.y);
        }

        uint2* lp = lds2 + (size_t)sub * 400 + lane;
        lp[0]   = make_uint2(h2u(aL0a), h2u(aL0b)); lp[50]  = make_uint2(h2u(aR0a), h2u(aR0b));
        lp[100] = make_uint2(h2u(aL1a), h2u(aL1b)); lp[150] = make_uint2(h2u(aR1a), h2u(aR1b));
        lp[200] = make_uint2(h2u(aL2a), h2u(aL2b)); lp[250] = make_uint2(h2u(aR2a), h2u(aR2b));
        lp[300] = make_uint2(h2u(aL3a), h2u(aL3b)); lp[350] = make_uint2(h2u(aR3a), h2u(aR3b));
    }
    __syncthreads();

    if (tid < 400) {
        int k = tid / 100;
        int r = tid - k * 100;
        int hf = r / 50;
        int ln = r - hf * 50;
        int slot = (k * 2 + hf) * 50 + ln;
        uint2 v = lds2[slot];
        h2 va = u2h2(v.x), vb = u2h2(v.y);
#pragma unroll
        for (int s2 = 1; s2 < 8; s2++) {
            uint2 w = lds2[s2 * 400 + slot];
            va = hmax2(va, u2h2(w.x));
            vb = hmax2(vb, u2h2(w.y));
        }
        int m = pg * 4 + k;
        if (m < NI)
            *(uint2*)(poolf + (size_t)(b * 256 + m + 1) * 416 + hf * 200 + ln * 4)
                = make_uint2(h2u(va), h2u(vb));
    } else if (tid < 464) {                        // zero K-pad cols 400..415
        int t = tid - 400;
        int k = t >> 4, c = t & 15;
        int m = pg * 4 + k;
        if (m < NI) poolf[(size_t)(b * 256 + m + 1) * 416 + 400 + c] = 0;
    }
}

// ---------------- D: fused FC GEMM, K-split x4 + bias + end padding -> out ------
// M=2048 (b,s), N=48. grid (3,64); 512 thr = 2 mtiles x 4 K-parts; 6KB LDS combine.
__global__ __launch_bounds__(512) void k_fc(const unsigned short* __restrict__ poolf,
                                            const unsigned short* __restrict__ tokb,
                                            const unsigned short* __restrict__ fcWb,
                                            const float* __restrict__ fcB,
                                            float* __restrict__ out) {
    __shared__ float4 cld[3 * 2 * 64];             // [kp-1][mt][lane] 6 KB
    int n0 = blockIdx.x * 16;
    int mg = blockIdx.y;
    int tid = threadIdx.x;
    int wave = tid >> 6;
    int lane = tid & 63;
    int mt = wave & 1;
    int kp = wave >> 1;
    int quad = lane >> 4;
    int lr = lane & 15;
    int mtile = mg * 2 + mt;
    int b = mtile >> 4;
    int s0 = (mtile & 15) << 4;

    const unsigned short* pa0 = poolf + ((size_t)(b * 256 + s0 + lr) * 416 + quad * 8);
    const unsigned short* pb0 = fcWb + ((size_t)(n0 + lr) * 1344 + quad * 8);
    const unsigned short* pa1 = tokb + ((size_t)(b * 258 + s0 + lr) * 300 + quad * 8);
    const unsigned short* pb1 = fcWb + ((size_t)(n0 + lr) * 1344 + 416 + quad * 8);

    f32x4 acc0 = {0.f, 0.f, 0.f, 0.f};
    f32x4 acc1 = {0.f, 0.f, 0.f, 0.f};
    if (kp == 0) {
#pragma unroll
        for (int u = 0; u + 1 < 11; u += 2) {      // pool u 0..9
            half8 a0 = load_h8(pa0 + u * 32);
            half8 b0 = load_h8(pb0 + u * 32);
            acc0 = __builtin_amdgcn_mfma_f32_16x16x32_f16(a0, b0, acc0, 0, 0, 0);
            half8 a1 = load_h8(pa0 + u * 32 + 32);
            half8 b1 = load_h8(pb0 + u * 32 + 32);
            acc1 = __builtin_amdgcn_mfma_f32_16x16x32_f16(a1, b1, acc1, 0, 0, 0);
        }
        {   // pool tail u=10
            half8 a0 = load_h8(pa0 + 10 * 32);
            half8 b0 = load_h8(pb0 + 10 * 32);
            acc0 = __builtin_amdgcn_mfma_f32_16x16x32_f16(a0, b0, acc0, 0, 0, 0);
        }
    } else if (kp == 1) {
        {   // pool u=11,12
            half8 a0 = load_h8(pa0 + 11 * 32);
            half8 b0 = load_h8(pb0 + 11 * 32);
            acc0 = __builtin_amdgcn_mfma_f32_16x16x32_f16(a0, b0, acc0, 0, 0, 0);
            half8 a1 = load_h8(pa0 + 12 * 32);
            half8 b1 = load_h8(pb0 + 12 * 32);
            acc1 = __builtin_amdgcn_mfma_f32_16x16x32_f16(a1, b1, acc1, 0, 0, 0);
        }
#pragma unroll
        for (int v = 0; v + 1 < 9; v += 2) {       // llf v 0..7
            half8 a0 = load_h8(pa1 + v * 32);
            half8 b0 = load_h8(pb1 + v * 32);
            acc0 = __builtin_amdgcn_mfma_f32_16x16x32_f16(a0, b0, acc0, 0, 0, 0);
            half8 a1 = load_h8(pa1 + v * 32 + 32);
            half8 b1 = load_h8(pb1 + v * 32 + 32);
            acc1 = __builtin_amdgcn_mfma_f32_16x16x32_f16(a1, b1, acc1, 0, 0, 0);
        }
        {   // llf tail v=8
            half8 a0 = load_h8(pa1 + 8 * 32);
            half8 b0 = load_h8(pb1 + 8 * 32);
            acc0 = __builtin_amdgcn_mfma_f32_16x16x32_f16(a0, b0, acc0, 0, 0, 0);
        }
    } else if (kp == 2) {
#pragma unroll
        for (int v = 9; v + 1 < 19; v += 2) {      // llf v 9..18
            half8 a0 = load_h8(pa1 + v * 32);
            half8 b0 = load_h8(pb1 + v * 32);
            acc0 = __builtin_amdgcn_mfma_f32_16x16x32_f16(a0, b0, acc0, 0, 0, 0);
            half8 a1 = load_h8(pa1 + v * 32 + 32);
            half8 b1 = load_h8(pb1 + v * 32 + 32);
            acc1 = __builtin_amdgcn_mfma_f32_16x16x32_f16(a1, b1, acc1, 0, 0, 0);
        }
    } else {
#pragma unroll
        for (int v = 19; v + 1 < 29; v += 2) {     // llf v 19..28
            half8 a0 = load_h8(pa1 + v * 32);
            half8 b0 = load_h8(pb1 + v * 32);
            acc0 = __builtin_amdgcn_mfma_f32_16x16x32_f16(a0, b0, acc0, 0, 0, 0);
            half8 a1 = load_h8(pa1 + v * 32 + 32);
            half8 b1 = load_h8(pb1 + v * 32 + 32);
            acc1 = __builtin_amdgcn_mfma_f32_16x16x32_f16(a1, b1, acc1, 0, 0, 0);
        }
    }
    f32x4 accw = acc0 + acc1;
    if (kp > 0) {
        cld[((kp - 1) * 2 + mt) * 64 + lane] = make_float4(accw[0], accw[1], accw[2], accw[3]);
    }
    __syncthreads();
    if (kp == 0) {
        float4 p1 = cld[(0 * 2 + mt) * 64 + lane];
        float4 p2 = cld[(1 * 2 + mt) * 64 + lane];
        float4 p3 = cld[(2 * 2 + mt) * 64 + lane];
        float r4[4] = {accw[0] + p1.x + p2.x + p3.x,
                       accw[1] + p1.y + p2.y + p3.y,
                       accw[2] + p1.z + p2.z + p3.z,
                       accw[3] + p1.w + p2.w + p3.w};
        int l = n0 + lr;
        if (l < L) {
            float bias = fcB[l];
#pragma unroll
            for (int r = 0; r < 4; r++) {
                int s = s0 + quad * 4 + r;
                float val;
                if (s == 0 || s == S - 1) val = (l == L - 1) ? 1.0f : 0.0f;
                else                      val = r4[r] + bias;
                out[(size_t)(b * 256 + s) * L + l] = val;
            }
        }
    }
}

extern "C" void kernel_launch(void* const* d_in, const int* in_sizes, int n_in,
                              void* d_out, int out_size, void* d_ws, size_t ws_size,
                              hipStream_t stream) {
    const int*   ids      = (const int*)d_in[0];
    const float* word_emb = (const float*)d_in[1];
    const float* pf_emb   = (const float*)d_in[2];
    const float* conv_W   = (const float*)d_in[3];
    const float* conv_b   = (const float*)d_in[4];
    const float* fc_W     = (const float*)d_in[5];
    const float* fc_b     = (const float*)d_in[6];
    float* out = (float*)d_out;
    float* ws  = (float*)d_ws;

    unsigned short* tokb  = (unsigned short*)(ws + TOKB_OFF);
    unsigned short* Wr3   = (unsigned short*)(ws + WR3_OFF);
    unsigned short* fcWb  = (unsigned short*)(ws + FCWB_OFF);
    unsigned short* g     = (unsigned short*)(ws + G_OFF);
    unsigned short* c0    = (unsigned short*)(ws + C0_OFF);
    unsigned short* c255  = (unsigned short*)(ws + C255_OFF);
    unsigned short* ct    = (unsigned short*)(ws + CT_OFF);
    unsigned short* poolf = (unsigned short*)(ws + POOLF_OFF);

    k_init<<<INIT_BLOCKS, 256, 0, stream>>>(ids, word_emb, conv_W, tokb, Wr3);
    k_conv<<<CONVD_BLOCKS, 512, 0, stream>>>(tokb, Wr3, conv_b, conv_W, fc_W,
                                             pf_emb, ct, fcWb, g, c0, c255);
    k_poolA<<<dim3(64, 8), 512, 0, stream>>>(ct, g, c0, c255, poolf);
    k_fc<<<dim3(3, 64), 512, 0, stream>>>(poolf, tokb, fcWb, fc_b, out);
}